// Round 1
// 281.273 us; speedup vs baseline: 1.1192x; 1.1192x over previous
//
#include <hip/hip_runtime.h>

#define D 256
#define B 128
#define S 64
#define L 32
#define K 32
#define KH 16
#define NW 8      // waves per recurrence block (512 threads), 32 cols/wave
#define NSUB 2    // 16-col sub-tiles per wave
#define HSTR 260  // u16 stride (proven 0-conflict R7/R8)

typedef _Float16 f16x8 __attribute__((ext_vector_type(8)));  // 8 f16 in 4 VGPRs
typedef float f32x4 __attribute__((ext_vector_type(4)));
typedef unsigned short u16;

__device__ __forceinline__ u16 h_bits(_Float16 h) {
    union { _Float16 h; u16 u; } x; x.h = h; return x.u;
}

// ---------------------------------------------------------------------------
// sent_mask extraction, robust to bool shipped as 1-byte or int32.
// ---------------------------------------------------------------------------
__global__ void mask_kernel(const void* mraw, int* mask_out) {
    __shared__ int flag;
    const int tid = threadIdx.x;
    if (tid == 0) flag = 0;
    __syncthreads();
    const unsigned int* w32 = (const unsigned int*)mraw;
    int loc = 0;
    for (int i = tid; i < 1024; i += 256)
        if (w32[i] > 1u) loc = 1;
    if (loc) flag = 1;   // benign race
    __syncthreads();
    const bool is_bytes = (flag != 0);
    const unsigned char* b8 = (const unsigned char*)mraw;
    const int* i32 = (const int*)mraw;
    for (int i = tid; i < B * S; i += 256)
        mask_out[i] = is_bytes ? (int)b8[(size_t)i * L] : i32[(size_t)i * L];
}

// ---------------------------------------------------------------------------
// enc_sents[b,s,:] = sum_l E[prgrph[b,s,l], :]  (2048 blocks, float4 gathers)
// MASK SKIP: enc/eW/ek for unmasked sentences are never consumed downstream
// (recur iterates set mask bits only) -> wave-uniform early-out halves the
// ~268 MB of gather traffic in expectation.
// ---------------------------------------------------------------------------
__global__ __launch_bounds__(256) void embed_kernel(
    const int* __restrict__ prgrph, const float* __restrict__ E,
    float* __restrict__ enc, const int* __restrict__ mask) {
    const int t = threadIdx.x;
    const int g = t >> 6;                // sentence within block (== wave id)
    const int bs = blockIdx.x * 4 + g;
    const int c4 = t & 63;               // float4 column group
    __shared__ int sidx[4][L];
    if (t < 4 * L) sidx[t >> 5][t & 31] = prgrph[(size_t)blockIdx.x * 4 * L + t];
    __syncthreads();
    if (!mask[bs]) return;               // wave-uniform: g == wave
    const float4* E4 = (const float4*)E;
    float4 a = make_float4(0.f, 0.f, 0.f, 0.f);
    #pragma unroll
    for (int l = 0; l < L; ++l) {
        const float4 v = E4[(size_t)sidx[g][l] * (D / 4) + c4];
        a.x += v.x; a.y += v.y; a.z += v.z; a.w += v.w;
    }
    *(float4*)&enc[(size_t)bs * D + c4 * 4] = a;
}

// ---------------------------------------------------------------------------
// Fused: O[r,:] = A[r,:] @ Bm for BOTH (enc@W -> eW) and (keys@V -> keysV).
// One dispatch instead of two; blocks < 256 do eW, the rest do keysV.
// ---------------------------------------------------------------------------
__global__ __launch_bounds__(256) void gemm2_kernel(
    const float* __restrict__ enc, const float* __restrict__ W,
    float* __restrict__ eW,
    const float* __restrict__ keys, const float* __restrict__ V,
    float* __restrict__ keysV) {
    const float* A; const float* Bm; float* O; int row0;
    if (blockIdx.x < (B * S) / 32) {
        A = enc; Bm = W; O = eW; row0 = blockIdx.x * 32;
    } else {
        A = keys; Bm = V; O = keysV; row0 = (blockIdx.x - (B * S) / 32) * 32;
    }
    const int t = threadIdx.x, wave = t >> 6, lane = t & 63;
    __shared__ float a_s[32 * D];
    const float4* Ag = (const float4*)(A + (size_t)row0 * D);
    float4* As4 = (float4*)a_s;
    for (int i = t; i < 32 * D / 4; i += 256) As4[i] = Ag[i];
    __syncthreads();
    const int r0 = wave * 8, c0 = lane * 4;
    float4 acc[8];
    #pragma unroll
    for (int i = 0; i < 8; ++i) acc[i] = make_float4(0.f, 0.f, 0.f, 0.f);
    for (int d = 0; d < D; d += 4) {
        float4 av[8];
        #pragma unroll
        for (int i = 0; i < 8; ++i) av[i] = *(const float4*)&a_s[(r0 + i) * D + d];
        #pragma unroll
        for (int j = 0; j < 4; ++j) {
            const float4 w = *(const float4*)(Bm + (size_t)(d + j) * D + c0);
            #pragma unroll
            for (int i = 0; i < 8; ++i) {
                const float a = (j == 0) ? av[i].x : (j == 1) ? av[i].y
                              : (j == 2) ? av[i].z : av[i].w;
                acc[i].x += a * w.x; acc[i].y += a * w.y;
                acc[i].z += a * w.z; acc[i].w += a * w.w;
            }
        }
    }
    #pragma unroll
    for (int i = 0; i < 8; ++i)
        *(float4*)&O[(size_t)(row0 + r0 + i) * D + c0] = acc[i];
}

// ---------------------------------------------------------------------------
// ek[b,s,k] = enc[b,s,:] . keys[b,k,:]   (mask-skip saves load traffic only;
// wave time bound by any masked lane, but unmasked threads drop their loads)
// ---------------------------------------------------------------------------
__global__ __launch_bounds__(256) void ek_kernel(
    const float* __restrict__ enc, const float* __restrict__ keys,
    float* __restrict__ ek, const int* __restrict__ mask) {
    const int b = blockIdx.x, t = threadIdx.x;
    __shared__ float ks[K][D + 4];
    const float4* kg = (const float4*)(keys + (size_t)b * K * D);
    for (int i = t; i < K * D / 4; i += 256)
        *(float4*)&ks[i >> 6][(i & 63) * 4] = kg[i];
    __syncthreads();
    const int s = t >> 2, kq = t & 3;          // k = kq + 4j
    if (!mask[b * S + s]) return;
    const float4* e4 = (const float4*)(enc + (size_t)(b * S + s) * D);
    float acc[8];
    #pragma unroll
    for (int j = 0; j < 8; ++j) acc[j] = 0.f;
    for (int d4 = 0; d4 < D / 4; ++d4) {
        const float4 e = e4[d4];
        #pragma unroll
        for (int j = 0; j < 8; ++j) {
            const float4 kv = *(const float4*)&ks[kq + 4 * j][d4 * 4];
            acc[j] += e.x * kv.x + e.y * kv.y + e.z * kv.z + e.w * kv.w;
        }
    }
    #pragma unroll
    for (int j = 0; j < 8; ++j)
        ek[(size_t)(b * S + s) * K + kq + 4 * j] = acc[j];
}

// ---------------------------------------------------------------------------
// Recurrence. Block = (b, 16-row half of K); 512 threads = 8 waves; wave w
// owns cols [32w,32w+32) = 2 sub-tiles. Lane (n=lane&15, quad=lane>>4):
// C/D row = quad*4+reg, col = 32w+16sub+n.
// KEY (R9 post-mortem): co-residency beats fewer rounds. U f16 hi/lo frags =
// 128 AGPRs/wave (asm "+a" pin, R8-proven); 2 blocks/CU, all 512 blocks in
// ONE occupancy round, 16 waves/CU.
// R10: __syncthreads drains vmcnt(0) -> exposed the latency of the
// next-step eWc/ekv/e_n prefetches on the serial path EVERY step. Only LDS
// carries cross-wave data here, so use lgkmcnt(0)+raw s_barrier (m201/HK
// pattern); prefetched global loads now stay in flight across the barrier.
// s_setprio(1) around the MFMA chain: 2 co-resident blocks are at different
// steps -> scheduler has role diversity to arbitrate (T5).
// ek is indexed by ABSOLUTE entity -> kh offset required (R3 bug).
// ---------------------------------------------------------------------------
__global__ __launch_bounds__(512, 2) void recur_kernel(
    const float* __restrict__ enc, const float* __restrict__ eWp,
    const float* __restrict__ keysV, const float* __restrict__ ek,
    const float* __restrict__ U, const int* __restrict__ mask,
    float* __restrict__ out) {
    const int b  = blockIdx.x >> 1;
    const int kh = (blockIdx.x & 1) * KH;
    const int t = threadIdx.x;
    const int wave = t >> 6, lane = t & 63;
    const int n = lane & 15, quad = lane >> 4;

    __shared__ u16 hF[2][KH][HSTR];      // 2 x 8.1 KB, f16 h planes
    __shared__ float redN[2][KH][NW];
    __shared__ float redG[2][KH][NW];

    // ---- preload U B-fragments (f16 hi/lo): 2 subs x 8 kt -> 128 AGPRs ----
    f16x8 Uhi[NSUB][8], Ulo[NSUB][8];
    #pragma unroll
    for (int sub = 0; sub < NSUB; ++sub) {
        const int col = wave * 32 + sub * 16 + n;
        #pragma unroll
        for (int kt = 0; kt < 8; ++kt) {
            #pragma unroll
            for (int j = 0; j < 8; ++j) {
                const int k = kt * 32 + quad * 8 + j;
                const float u = U[(size_t)k * D + col];
                const _Float16 uh = (_Float16)u;
                Uhi[sub][kt][j] = uh;
                Ulo[sub][kt][j] = (_Float16)(u - (float)uh);
            }
        }
    }
    #pragma unroll
    for (int sub = 0; sub < NSUB; ++sub)
        #pragma unroll
        for (int kt = 0; kt < 8; ++kt)
            asm volatile("" : "+a"(Uhi[sub][kt]), "+a"(Ulo[sub][kt]));

    // ---- per-lane state ----
    float upv[4][NSUB];
    float rn[4];
    float keysVc[4][NSUB];
    #pragma unroll
    for (int reg = 0; reg < 4; ++reg) {
        rn[reg] = 1.f;
        const size_t base = (size_t)(b * K + kh + quad * 4 + reg) * D;
        #pragma unroll
        for (int sub = 0; sub < NSUB; ++sub) {
            upv[reg][sub] = 0.f;
            keysVc[reg][sub] = keysV[base + wave * 32 + sub * 16 + n];
        }
    }

    const int* bm = mask + b * S;
    unsigned long long rem = __ballot(bm[lane & 63] != 0);

    float eWc[NSUB];
    float4 ekv = make_float4(0.f, 0.f, 0.f, 0.f);
    #pragma unroll
    for (int sub = 0; sub < NSUB; ++sub) eWc[sub] = 0.f;
    if (rem) {
        const int s0 = (int)__builtin_ctzll(rem);
        const size_t eo = (size_t)(b * S + s0) * D;
        #pragma unroll
        for (int sub = 0; sub < NSUB; ++sub)
            eWc[sub] = eWp[eo + wave * 32 + sub * 16 + n];
        ekv = *(const float4*)(ek + (size_t)(b * S + s0) * K + kh + quad * 4);
    }

    int p = 0, q = 0;
    bool first = true;
    while (rem) {
        rem &= rem - 1;
        const int sn = rem ? (int)__builtin_ctzll(rem) : -1;

        // ---- issue next-step e load early (covered by MFMA) ----
        float e_n[NSUB];
        #pragma unroll
        for (int sub = 0; sub < NSUB; ++sub) e_n[sub] = 0.f;
        if (sn >= 0) {
            const size_t eo = (size_t)(b * S + sn) * D;
            #pragma unroll
            for (int sub = 0; sub < NSUB; ++sub)
                e_n[sub] = enc[eo + wave * 32 + sub * 16 + n];
        }

        // ---- MFMA: acc = h_prev @ (Uhi,Ulo), 4 indep chains of 8 ----
        f32x4 acc[NSUB][2];
        #pragma unroll
        for (int sub = 0; sub < NSUB; ++sub) {
            acc[sub][0] = (f32x4){0.f, 0.f, 0.f, 0.f};
            acc[sub][1] = (f32x4){0.f, 0.f, 0.f, 0.f};
        }
        if (!first) {
            __builtin_amdgcn_s_setprio(1);
            #pragma unroll
            for (int kt = 0; kt < 8; ++kt) {
                const f16x8 av = *(const f16x8*)&hF[p][n][kt * 32 + quad * 8];
                #pragma unroll
                for (int sub = 0; sub < NSUB; ++sub) {
                    acc[sub][0] = __builtin_amdgcn_mfma_f32_16x16x32_f16(av, Uhi[sub][kt], acc[sub][0], 0, 0, 0);
                    acc[sub][1] = __builtin_amdgcn_mfma_f32_16x16x32_f16(av, Ulo[sub][kt], acc[sub][1], 0, 0, 0);
                }
            }
            __builtin_amdgcn_s_setprio(0);
        }

        // ---- gate ----
        float gate[4];
        #pragma unroll
        for (int reg = 0; reg < 4; ++reg) {
            const float ekb = (reg == 0) ? ekv.x : (reg == 1) ? ekv.y
                            : (reg == 2) ? ekv.z : ekv.w;
            float g = ekb;
            if (!first) {
                const float* rg = redG[q ^ 1][quad * 4 + reg];
                const float4 g0 = *(const float4*)rg;
                const float4 g1 = *(const float4*)(rg + 4);
                g += rn[reg] * (g0.x + g0.y + g0.z + g0.w +
                                g1.x + g1.y + g1.z + g1.w);
            }
            gate[reg] = 1.f / (1.f + __expf(-g));
        }

        // ---- update + f16 h write + norm/gate-dot partials ----
        const int pw = p ^ 1;
        float pn[4], gd[4];
        #pragma unroll
        for (int reg = 0; reg < 4; ++reg) {
            const int row = quad * 4 + reg;
            float sq = 0.f, dv = 0.f;
            #pragma unroll
            for (int sub = 0; sub < NSUB; ++sub) {
                const float asum = acc[sub][0][reg] + acc[sub][1][reg];
                float ht = rn[reg] * asum + keysVc[reg][sub] + eWc[sub];
                ht = fmaxf(ht, 0.f);
                const float u2 = rn[reg] * upv[reg][sub] + gate[reg] * ht;
                upv[reg][sub] = u2;
                sq += u2 * u2;
                dv += u2 * e_n[sub];
                hF[pw][row][wave * 32 + sub * 16 + n] = h_bits((_Float16)u2);
            }
            pn[reg] = sq;
            gd[reg] = dv;
        }

        // ---- reload step-invariants IN PLACE (last use passed) ----
        // These loads now stay in flight ACROSS the barrier (no vmcnt drain).
        if (sn >= 0) {
            const size_t eo = (size_t)(b * S + sn) * D;
            #pragma unroll
            for (int sub = 0; sub < NSUB; ++sub)
                eWc[sub] = eWp[eo + wave * 32 + sub * 16 + n];
            ekv = *(const float4*)(ek + (size_t)(b * S + sn) * K + kh + quad * 4);
        }

        #pragma unroll
        for (int m = 1; m <= 8; m <<= 1) {
            #pragma unroll
            for (int reg = 0; reg < 4; ++reg) {
                pn[reg] += __shfl_xor(pn[reg], m);
                gd[reg] += __shfl_xor(gd[reg], m);
            }
        }
        if (n == 0) {
            #pragma unroll
            for (int reg = 0; reg < 4; ++reg) {
                redN[q][quad * 4 + reg][wave] = pn[reg];
                redG[q][quad * 4 + reg][wave] = gd[reg];
            }
        }

        // ---- the ONLY barrier: LDS-only dependency -> no vmcnt(0) drain ----
        asm volatile("s_waitcnt lgkmcnt(0)" ::: "memory");
        __builtin_amdgcn_s_barrier();

        #pragma unroll
        for (int reg = 0; reg < 4; ++reg) {
            const float* rp = redN[q][quad * 4 + reg];
            const float4 r0 = *(const float4*)rp;
            const float4 r1 = *(const float4*)(rp + 4);
            rn[reg] = rsqrtf(fmaxf(r0.x + r0.y + r0.z + r0.w +
                                   r1.x + r1.y + r1.z + r1.w, 1e-12f));
        }
        p ^= 1; q ^= 1; first = false;
    }

    #pragma unroll
    for (int reg = 0; reg < 4; ++reg) {
        const size_t base = (size_t)(b * K + kh + quad * 4 + reg) * D;
        #pragma unroll
        for (int sub = 0; sub < NSUB; ++sub)
            out[base + wave * 32 + sub * 16 + n] = rn[reg] * upv[reg][sub];
    }
}

extern "C" void kernel_launch(void* const* d_in, const int* in_sizes, int n_in,
                              void* d_out, int out_size, void* d_ws, size_t ws_size,
                              hipStream_t stream) {
    const int*   prgrph = (const int*)d_in[0];
    const void*  pmask  = d_in[1];
    const float* keys   = (const float*)d_in[2];
    const float* E      = (const float*)d_in[3];
    const float* U      = (const float*)d_in[4];
    const float* V      = (const float*)d_in[5];
    const float* W      = (const float*)d_in[6];
    float* out = (float*)d_out;

    float* ws_enc   = (float*)d_ws;                          // B*S*D  (8 MB)
    float* ws_eW    = ws_enc + (size_t)B * S * D;            // B*S*D  (8 MB)
    float* ws_keysV = ws_eW  + (size_t)B * S * D;            // B*K*D  (4 MB)
    float* ws_ek    = ws_keysV + (size_t)B * K * D;          // B*S*K  (1 MB)
    int*   ws_mask  = (int*)(ws_ek + (size_t)B * S * K);     // B*S

    mask_kernel<<<1, 256, 0, stream>>>(pmask, ws_mask);
    embed_kernel<<<(B * S) / 4, 256, 0, stream>>>(prgrph, E, ws_enc, ws_mask);
    gemm2_kernel<<<(B * S) / 32 + (B * K) / 32, 256, 0, stream>>>(
        ws_enc, W, ws_eW, keys, V, ws_keysV);
    ek_kernel<<<B, 256, 0, stream>>>(ws_enc, keys, ws_ek, ws_mask);
    recur_kernel<<<B * (K / KH), 512, 0, stream>>>(
        ws_enc, ws_eW, ws_keysV, ws_ek, U, ws_mask, out);
}

// Round 2
// 276.233 us; speedup vs baseline: 1.1397x; 1.0182x over previous
//
#include <hip/hip_runtime.h>

#define D 256
#define B 128
#define S 64
#define L 32
#define K 32
#define KH 16
#define NW 8      // waves per recurrence block (512 threads), 32 cols/wave
#define NSUB 2    // 16-col sub-tiles per wave
#define HSTR 260  // u16 stride (proven 0-conflict R7/R8)

typedef _Float16 f16x8 __attribute__((ext_vector_type(8)));  // 8 f16 in 4 VGPRs
typedef float f32x4 __attribute__((ext_vector_type(4)));
typedef unsigned short u16;

__device__ __forceinline__ u16 h_bits(_Float16 h) {
    union { _Float16 h; u16 u; } x; x.h = h; return x.u;
}

// ---------------------------------------------------------------------------
// sent_mask extraction, robust to bool shipped as 1-byte or int32.
// ---------------------------------------------------------------------------
__global__ void mask_kernel(const void* mraw, int* mask_out) {
    __shared__ int flag;
    const int tid = threadIdx.x;
    if (tid == 0) flag = 0;
    __syncthreads();
    const unsigned int* w32 = (const unsigned int*)mraw;
    int loc = 0;
    for (int i = tid; i < 1024; i += 256)
        if (w32[i] > 1u) loc = 1;
    if (loc) flag = 1;   // benign race
    __syncthreads();
    const bool is_bytes = (flag != 0);
    const unsigned char* b8 = (const unsigned char*)mraw;
    const int* i32 = (const int*)mraw;
    for (int i = tid; i < B * S; i += 256)
        mask_out[i] = is_bytes ? (int)b8[(size_t)i * L] : i32[(size_t)i * L];
}

// ---------------------------------------------------------------------------
// enc_sents[b,s,:] = sum_l E[prgrph[b,s,l], :]  (2048 blocks, float4 gathers)
// MASK SKIP: enc/eW/ek for unmasked sentences are never consumed downstream
// (recur iterates set mask bits only) -> wave-uniform early-out halves the
// ~268 MB of gather traffic in expectation.
// ---------------------------------------------------------------------------
__global__ __launch_bounds__(256) void embed_kernel(
    const int* __restrict__ prgrph, const float* __restrict__ E,
    float* __restrict__ enc, const int* __restrict__ mask) {
    const int t = threadIdx.x;
    const int g = t >> 6;                // sentence within block (== wave id)
    const int bs = blockIdx.x * 4 + g;
    const int c4 = t & 63;               // float4 column group
    __shared__ int sidx[4][L];
    if (t < 4 * L) sidx[t >> 5][t & 31] = prgrph[(size_t)blockIdx.x * 4 * L + t];
    __syncthreads();
    if (!mask[bs]) return;               // wave-uniform: g == wave
    const float4* E4 = (const float4*)E;
    float4 a = make_float4(0.f, 0.f, 0.f, 0.f);
    #pragma unroll
    for (int l = 0; l < L; ++l) {
        const float4 v = E4[(size_t)sidx[g][l] * (D / 4) + c4];
        a.x += v.x; a.y += v.y; a.z += v.z; a.w += v.w;
    }
    *(float4*)&enc[(size_t)bs * D + c4 * 4] = a;
}

// ---------------------------------------------------------------------------
// Fused: O[r,:] = A[r,:] @ Bm for BOTH (enc@W -> eW) and (keys@V -> keysV).
// One dispatch instead of two; blocks < 256 do eW, the rest do keysV.
// ---------------------------------------------------------------------------
__global__ __launch_bounds__(256) void gemm2_kernel(
    const float* __restrict__ enc, const float* __restrict__ W,
    float* __restrict__ eW,
    const float* __restrict__ keys, const float* __restrict__ V,
    float* __restrict__ keysV) {
    const float* A; const float* Bm; float* O; int row0;
    if (blockIdx.x < (B * S) / 32) {
        A = enc; Bm = W; O = eW; row0 = blockIdx.x * 32;
    } else {
        A = keys; Bm = V; O = keysV; row0 = (blockIdx.x - (B * S) / 32) * 32;
    }
    const int t = threadIdx.x, wave = t >> 6, lane = t & 63;
    __shared__ float a_s[32 * D];
    const float4* Ag = (const float4*)(A + (size_t)row0 * D);
    float4* As4 = (float4*)a_s;
    for (int i = t; i < 32 * D / 4; i += 256) As4[i] = Ag[i];
    __syncthreads();
    const int r0 = wave * 8, c0 = lane * 4;
    float4 acc[8];
    #pragma unroll
    for (int i = 0; i < 8; ++i) acc[i] = make_float4(0.f, 0.f, 0.f, 0.f);
    for (int d = 0; d < D; d += 4) {
        float4 av[8];
        #pragma unroll
        for (int i = 0; i < 8; ++i) av[i] = *(const float4*)&a_s[(r0 + i) * D + d];
        #pragma unroll
        for (int j = 0; j < 4; ++j) {
            const float4 w = *(const float4*)(Bm + (size_t)(d + j) * D + c0);
            #pragma unroll
            for (int i = 0; i < 8; ++i) {
                const float a = (j == 0) ? av[i].x : (j == 1) ? av[i].y
                              : (j == 2) ? av[i].z : av[i].w;
                acc[i].x += a * w.x; acc[i].y += a * w.y;
                acc[i].z += a * w.z; acc[i].w += a * w.w;
            }
        }
    }
    #pragma unroll
    for (int i = 0; i < 8; ++i)
        *(float4*)&O[(size_t)(row0 + r0 + i) * D + c0] = acc[i];
}

// ---------------------------------------------------------------------------
// ek[b,s,k] = enc[b,s,:] . keys[b,k,:]   (mask-skip saves load traffic only)
// ---------------------------------------------------------------------------
__global__ __launch_bounds__(256) void ek_kernel(
    const float* __restrict__ enc, const float* __restrict__ keys,
    float* __restrict__ ek, const int* __restrict__ mask) {
    const int b = blockIdx.x, t = threadIdx.x;
    __shared__ float ks[K][D + 4];
    const float4* kg = (const float4*)(keys + (size_t)b * K * D);
    for (int i = t; i < K * D / 4; i += 256)
        *(float4*)&ks[i >> 6][(i & 63) * 4] = kg[i];
    __syncthreads();
    const int s = t >> 2, kq = t & 3;          // k = kq + 4j
    if (!mask[b * S + s]) return;
    const float4* e4 = (const float4*)(enc + (size_t)(b * S + s) * D);
    float acc[8];
    #pragma unroll
    for (int j = 0; j < 8; ++j) acc[j] = 0.f;
    for (int d4 = 0; d4 < D / 4; ++d4) {
        const float4 e = e4[d4];
        #pragma unroll
        for (int j = 0; j < 8; ++j) {
            const float4 kv = *(const float4*)&ks[kq + 4 * j][d4 * 4];
            acc[j] += e.x * kv.x + e.y * kv.y + e.z * kv.z + e.w * kv.w;
        }
    }
    #pragma unroll
    for (int j = 0; j < 8; ++j)
        ek[(size_t)(b * S + s) * K + kq + 4 * j] = acc[j];
}

// ---------------------------------------------------------------------------
// Recurrence. Block = (b, 16-row half of K); 512 threads = 8 waves; wave w
// owns cols [32w,32w+32) = 2 sub-tiles. Lane (n=lane&15, quad=lane>>4):
// C/D row = quad*4+reg, col = 32w+16sub+n.
// KEY (R9 post-mortem): co-residency beats fewer rounds. U f16 hi/lo frags =
// 128 AGPRs/wave (asm "+a" pin, R8-proven); 2 blocks/CU, all 512 blocks in
// ONE occupancy round, 16 waves/CU.
// R10/R11: __syncthreads drains vmcnt(0) -> kills the next-step prefetch
// cover. Only LDS carries cross-wave data -> lgkmcnt(0) + raw s_barrier
// (compiler fences on BOTH sides: clang may otherwise hoist post-barrier
// redN ds_reads above the bare s_barrier intrinsic).
// R11: s_setprio REMOVED — T5 is negative on lockstep barrier-synced
// structures (m190); it starved the co-resident block's waves, serializing
// the two blocks instead of interleaving them (122.7 vs 109 µs).
// ek is indexed by ABSOLUTE entity -> kh offset required (R3 bug).
// ---------------------------------------------------------------------------
__global__ __launch_bounds__(512, 2) void recur_kernel(
    const float* __restrict__ enc, const float* __restrict__ eWp,
    const float* __restrict__ keysV, const float* __restrict__ ek,
    const float* __restrict__ U, const int* __restrict__ mask,
    float* __restrict__ out) {
    const int b  = blockIdx.x >> 1;
    const int kh = (blockIdx.x & 1) * KH;
    const int t = threadIdx.x;
    const int wave = t >> 6, lane = t & 63;
    const int n = lane & 15, quad = lane >> 4;

    __shared__ u16 hF[2][KH][HSTR];      // 2 x 8.1 KB, f16 h planes
    __shared__ float redN[2][KH][NW];
    __shared__ float redG[2][KH][NW];

    // ---- preload U B-fragments (f16 hi/lo): 2 subs x 8 kt -> 128 AGPRs ----
    f16x8 Uhi[NSUB][8], Ulo[NSUB][8];
    #pragma unroll
    for (int sub = 0; sub < NSUB; ++sub) {
        const int col = wave * 32 + sub * 16 + n;
        #pragma unroll
        for (int kt = 0; kt < 8; ++kt) {
            #pragma unroll
            for (int j = 0; j < 8; ++j) {
                const int k = kt * 32 + quad * 8 + j;
                const float u = U[(size_t)k * D + col];
                const _Float16 uh = (_Float16)u;
                Uhi[sub][kt][j] = uh;
                Ulo[sub][kt][j] = (_Float16)(u - (float)uh);
            }
        }
    }
    #pragma unroll
    for (int sub = 0; sub < NSUB; ++sub)
        #pragma unroll
        for (int kt = 0; kt < 8; ++kt)
            asm volatile("" : "+a"(Uhi[sub][kt]), "+a"(Ulo[sub][kt]));

    // ---- per-lane state ----
    float upv[4][NSUB];
    float rn[4];
    float keysVc[4][NSUB];
    #pragma unroll
    for (int reg = 0; reg < 4; ++reg) {
        rn[reg] = 1.f;
        const size_t base = (size_t)(b * K + kh + quad * 4 + reg) * D;
        #pragma unroll
        for (int sub = 0; sub < NSUB; ++sub) {
            upv[reg][sub] = 0.f;
            keysVc[reg][sub] = keysV[base + wave * 32 + sub * 16 + n];
        }
    }

    const int* bm = mask + b * S;
    unsigned long long rem = __ballot(bm[lane & 63] != 0);

    float eWc[NSUB];
    float4 ekv = make_float4(0.f, 0.f, 0.f, 0.f);
    #pragma unroll
    for (int sub = 0; sub < NSUB; ++sub) eWc[sub] = 0.f;
    if (rem) {
        const int s0 = (int)__builtin_ctzll(rem);
        const size_t eo = (size_t)(b * S + s0) * D;
        #pragma unroll
        for (int sub = 0; sub < NSUB; ++sub)
            eWc[sub] = eWp[eo + wave * 32 + sub * 16 + n];
        ekv = *(const float4*)(ek + (size_t)(b * S + s0) * K + kh + quad * 4);
    }

    int p = 0, q = 0;
    bool first = true;
    while (rem) {
        rem &= rem - 1;
        const int sn = rem ? (int)__builtin_ctzll(rem) : -1;

        // ---- issue next-step e load early (covered by MFMA) ----
        float e_n[NSUB];
        #pragma unroll
        for (int sub = 0; sub < NSUB; ++sub) e_n[sub] = 0.f;
        if (sn >= 0) {
            const size_t eo = (size_t)(b * S + sn) * D;
            #pragma unroll
            for (int sub = 0; sub < NSUB; ++sub)
                e_n[sub] = enc[eo + wave * 32 + sub * 16 + n];
        }

        // ---- MFMA: acc = h_prev @ (Uhi,Ulo), 4 indep chains of 8 ----
        f32x4 acc[NSUB][2];
        #pragma unroll
        for (int sub = 0; sub < NSUB; ++sub) {
            acc[sub][0] = (f32x4){0.f, 0.f, 0.f, 0.f};
            acc[sub][1] = (f32x4){0.f, 0.f, 0.f, 0.f};
        }
        if (!first) {
            #pragma unroll
            for (int kt = 0; kt < 8; ++kt) {
                const f16x8 av = *(const f16x8*)&hF[p][n][kt * 32 + quad * 8];
                #pragma unroll
                for (int sub = 0; sub < NSUB; ++sub) {
                    acc[sub][0] = __builtin_amdgcn_mfma_f32_16x16x32_f16(av, Uhi[sub][kt], acc[sub][0], 0, 0, 0);
                    acc[sub][1] = __builtin_amdgcn_mfma_f32_16x16x32_f16(av, Ulo[sub][kt], acc[sub][1], 0, 0, 0);
                }
            }
        }

        // ---- gate ----
        float gate[4];
        #pragma unroll
        for (int reg = 0; reg < 4; ++reg) {
            const float ekb = (reg == 0) ? ekv.x : (reg == 1) ? ekv.y
                            : (reg == 2) ? ekv.z : ekv.w;
            float g = ekb;
            if (!first) {
                const float* rg = redG[q ^ 1][quad * 4 + reg];
                const float4 g0 = *(const float4*)rg;
                const float4 g1 = *(const float4*)(rg + 4);
                g += rn[reg] * (g0.x + g0.y + g0.z + g0.w +
                                g1.x + g1.y + g1.z + g1.w);
            }
            gate[reg] = 1.f / (1.f + __expf(-g));
        }

        // ---- update + f16 h write + norm/gate-dot partials ----
        const int pw = p ^ 1;
        float pn[4], gd[4];
        #pragma unroll
        for (int reg = 0; reg < 4; ++reg) {
            const int row = quad * 4 + reg;
            float sq = 0.f, dv = 0.f;
            #pragma unroll
            for (int sub = 0; sub < NSUB; ++sub) {
                const float asum = acc[sub][0][reg] + acc[sub][1][reg];
                float ht = rn[reg] * asum + keysVc[reg][sub] + eWc[sub];
                ht = fmaxf(ht, 0.f);
                const float u2 = rn[reg] * upv[reg][sub] + gate[reg] * ht;
                upv[reg][sub] = u2;
                sq += u2 * u2;
                dv += u2 * e_n[sub];
                hF[pw][row][wave * 32 + sub * 16 + n] = h_bits((_Float16)u2);
            }
            pn[reg] = sq;
            gd[reg] = dv;
        }

        // ---- reload step-invariants IN PLACE (last use passed) ----
        // These loads stay in flight ACROSS the barrier (no vmcnt drain).
        if (sn >= 0) {
            const size_t eo = (size_t)(b * S + sn) * D;
            #pragma unroll
            for (int sub = 0; sub < NSUB; ++sub)
                eWc[sub] = eWp[eo + wave * 32 + sub * 16 + n];
            ekv = *(const float4*)(ek + (size_t)(b * S + sn) * K + kh + quad * 4);
        }

        #pragma unroll
        for (int m = 1; m <= 8; m <<= 1) {
            #pragma unroll
            for (int reg = 0; reg < 4; ++reg) {
                pn[reg] += __shfl_xor(pn[reg], m);
                gd[reg] += __shfl_xor(gd[reg], m);
            }
        }
        if (n == 0) {
            #pragma unroll
            for (int reg = 0; reg < 4; ++reg) {
                redN[q][quad * 4 + reg][wave] = pn[reg];
                redG[q][quad * 4 + reg][wave] = gd[reg];
            }
        }

        // ---- the ONLY barrier: LDS-only dependency -> no vmcnt(0) drain.
        // Compiler fences on both sides keep post-barrier ds_reads from
        // being scheduled into the barrier window.
        asm volatile("s_waitcnt lgkmcnt(0)" ::: "memory");
        __builtin_amdgcn_s_barrier();
        asm volatile("" ::: "memory");

        #pragma unroll
        for (int reg = 0; reg < 4; ++reg) {
            const float* rp = redN[q][quad * 4 + reg];
            const float4 r0 = *(const float4*)rp;
            const float4 r1 = *(const float4*)(rp + 4);
            rn[reg] = rsqrtf(fmaxf(r0.x + r0.y + r0.z + r0.w +
                                   r1.x + r1.y + r1.z + r1.w, 1e-12f));
        }
        p ^= 1; q ^= 1; first = false;
    }

    #pragma unroll
    for (int reg = 0; reg < 4; ++reg) {
        const size_t base = (size_t)(b * K + kh + quad * 4 + reg) * D;
        #pragma unroll
        for (int sub = 0; sub < NSUB; ++sub)
            out[base + wave * 32 + sub * 16 + n] = rn[reg] * upv[reg][sub];
    }
}

extern "C" void kernel_launch(void* const* d_in, const int* in_sizes, int n_in,
                              void* d_out, int out_size, void* d_ws, size_t ws_size,
                              hipStream_t stream) {
    const int*   prgrph = (const int*)d_in[0];
    const void*  pmask  = d_in[1];
    const float* keys   = (const float*)d_in[2];
    const float* E      = (const float*)d_in[3];
    const float* U      = (const float*)d_in[4];
    const float* V      = (const float*)d_in[5];
    const float* W      = (const float*)d_in[6];
    float* out = (float*)d_out;

    float* ws_enc   = (float*)d_ws;                          // B*S*D  (8 MB)
    float* ws_eW    = ws_enc + (size_t)B * S * D;            // B*S*D  (8 MB)
    float* ws_keysV = ws_eW  + (size_t)B * S * D;            // B*K*D  (4 MB)
    float* ws_ek    = ws_keysV + (size_t)B * K * D;          // B*S*K  (1 MB)
    int*   ws_mask  = (int*)(ws_ek + (size_t)B * S * K);     // B*S

    mask_kernel<<<1, 256, 0, stream>>>(pmask, ws_mask);
    embed_kernel<<<(B * S) / 4, 256, 0, stream>>>(prgrph, E, ws_enc, ws_mask);
    gemm2_kernel<<<(B * S) / 32 + (B * K) / 32, 256, 0, stream>>>(
        ws_enc, W, ws_eW, keys, V, ws_keysV);
    ek_kernel<<<B, 256, 0, stream>>>(ws_enc, keys, ws_ek, ws_mask);
    recur_kernel<<<B * (K / KH), 512, 0, stream>>>(
        ws_enc, ws_eW, ws_keysV, ws_ek, U, ws_mask, out);
}

// Round 3
// 238.364 us; speedup vs baseline: 1.3207x; 1.1589x over previous
//
#include <hip/hip_runtime.h>

#define D 256
#define B 128
#define S 64
#define L 32
#define K 32
#define KH 16
#define NW 8      // waves per recurrence block (512 threads), 32 cols/wave
#define NSUB 2    // 16-col sub-tiles per wave
#define HSTR 260  // u16 stride (proven 0-conflict R7/R8)

typedef _Float16 f16x8 __attribute__((ext_vector_type(8)));  // 8 f16 in 4 VGPRs
typedef float f32x4 __attribute__((ext_vector_type(4)));
typedef unsigned short u16;

__device__ __forceinline__ u16 h_bits(_Float16 h) {
    union { _Float16 h; u16 u; } x; x.h = h; return x.u;
}

// ---------------------------------------------------------------------------
// sent_mask extraction, robust to bool shipped as 1-byte or int32.
// R12: widened 1 block -> 32 blocks; the old single-block version was a
// serial ~10µs latency-bound tail at the head of the graph.
// ---------------------------------------------------------------------------
__global__ __launch_bounds__(256) void mask_kernel(const void* mraw, int* mask_out) {
    __shared__ int flag;
    const int tid = threadIdx.x;
    if (tid == 0) flag = 0;
    __syncthreads();
    const unsigned int* w32 = (const unsigned int*)mraw;
    int loc = 0;
    #pragma unroll
    for (int j = 0; j < 4; ++j)
        if (w32[tid * 4 + j] > 1u) loc = 1;   // byte-packed bools leave >1 words
    if (loc) flag = 1;   // benign race
    __syncthreads();
    const bool is_bytes = (flag != 0);
    const unsigned char* b8 = (const unsigned char*)mraw;
    const int* i32 = (const int*)mraw;
    const int i = blockIdx.x * 256 + tid;     // 32 blocks x 256 = B*S
    mask_out[i] = is_bytes ? (int)b8[(size_t)i * L] : i32[(size_t)i * L];
}

// ---------------------------------------------------------------------------
// R12 fused pre-kernel (5 dispatches -> 3 total): blocks [0,256) each own 32
// consecutive (b,s) rows = half a batch:
//   A) embed-gather the 32 enc rows directly into LDS (and global, for recur's
//      e_n loads) -- masked rows skipped (never read downstream);
//   B) eW = enc @ W from LDS (each wave consumes only its own 8 rows);
//   C) stage keys[b], ek[s,k] = enc[s,:].keys[k,:] from LDS.
// Blocks [256,384): keysV = keys @ V (plain gemm path).
// LDS 71 KB -> 2 blocks/CU. a_s padded to 264 floats (phase-C row reads:
// 8 s_locals/wave at stride 264 -> 2-way bank overlap = free, m136).
// ---------------------------------------------------------------------------
__global__ __launch_bounds__(256) void pre_kernel(
    const int* __restrict__ prgrph, const float* __restrict__ E,
    const float* __restrict__ Wm, const float* __restrict__ Vm,
    const float* __restrict__ keys, const int* __restrict__ mask,
    float* __restrict__ enc, float* __restrict__ eW,
    float* __restrict__ keysV, float* __restrict__ ek) {
    const int t = threadIdx.x, wave = t >> 6, lane = t & 63;
    __shared__ int   sidx[32][L];        // 4 KB
    __shared__ float a_s[32][264];       // 33.8 KB (padded)
    __shared__ float ks[32][260];        // 33.3 KB (padded, matches old ek)

    const float* Bm;
    float* O;

    if (blockIdx.x < (B * S) / 32) {
        const int bid = blockIdx.x;          // b = bid>>1, half = bid&1
        const int b = bid >> 1;

        // ---- stage prgrph indices: 32 sentences x 32 tokens, contiguous ----
        #pragma unroll
        for (int j = 0; j < 4; ++j) {
            const int idx = t * 4 + j;
            sidx[idx >> 5][idx & 31] = prgrph[(size_t)bid * 1024 + idx];
        }
        __syncthreads();

        // ---- phase A: gather own 8 rows (wave-uniform mask skip) ----
        const float4* E4 = (const float4*)E;
        for (int sl = wave * 8; sl < wave * 8 + 8; ++sl) {
            if (!mask[bid * 32 + sl]) continue;
            float4 a = make_float4(0.f, 0.f, 0.f, 0.f);
            #pragma unroll
            for (int l = 0; l < L; ++l) {
                const float4 v = E4[(size_t)sidx[sl][l] * (D / 4) + lane];
                a.x += v.x; a.y += v.y; a.z += v.z; a.w += v.w;
            }
            *(float4*)&a_s[sl][lane * 4] = a;
            *(float4*)&enc[(size_t)(bid * 32 + sl) * D + lane * 4] = a;
        }
        __syncthreads();
        Bm = Wm;
        O = eW + (size_t)bid * 32 * D;
    } else {
        const int row0 = (blockIdx.x - (B * S) / 32) * 32;
        const float4* Ag = (const float4*)(keys + (size_t)row0 * D);
        for (int i = t; i < 32 * D / 4; i += 256) {
            const float4 v = Ag[i];
            *(float4*)&a_s[i >> 6][(i & 63) * 4] = v;
        }
        __syncthreads();
        Bm = Vm;
        O = keysV + (size_t)row0 * D;
    }

    // ---- phase B: 32xD @ DxD gemm, wave reads its own 8 rows (broadcast) ----
    {
        const int r0 = wave * 8, c0 = lane * 4;
        float4 acc[8];
        #pragma unroll
        for (int i = 0; i < 8; ++i) acc[i] = make_float4(0.f, 0.f, 0.f, 0.f);
        for (int d = 0; d < D; d += 4) {
            float4 av[8];
            #pragma unroll
            for (int i = 0; i < 8; ++i) av[i] = *(const float4*)&a_s[r0 + i][d];
            #pragma unroll
            for (int j = 0; j < 4; ++j) {
                const float4 w = *(const float4*)(Bm + (size_t)(d + j) * D + c0);
                #pragma unroll
                for (int i = 0; i < 8; ++i) {
                    const float a = (j == 0) ? av[i].x : (j == 1) ? av[i].y
                                  : (j == 2) ? av[i].z : av[i].w;
                    acc[i].x += a * w.x; acc[i].y += a * w.y;
                    acc[i].z += a * w.z; acc[i].w += a * w.w;
                }
            }
        }
        #pragma unroll
        for (int i = 0; i < 8; ++i)
            *(float4*)&O[(size_t)(r0 + i) * D + c0] = acc[i];
    }

    if (blockIdx.x >= (B * S) / 32) return;

    // ---- phase C: ek for own 32 sentences ----
    {
        const int bid = blockIdx.x;
        const int b = bid >> 1;
        const float4* kg = (const float4*)(keys + (size_t)b * K * D);
        for (int i = t; i < K * D / 4; i += 256) {
            const float4 v = kg[i];
            *(float4*)&ks[i >> 6][(i & 63) * 4] = v;
        }
        __syncthreads();
        const int sl = t >> 3, kq = t & 7;           // k = kq + 8j
        if (mask[bid * 32 + sl]) {
            float acc[4];
            #pragma unroll
            for (int j = 0; j < 4; ++j) acc[j] = 0.f;
            for (int d4 = 0; d4 < D / 4; ++d4) {
                const float4 e = *(const float4*)&a_s[sl][d4 * 4];
                #pragma unroll
                for (int j = 0; j < 4; ++j) {
                    const float4 kv = *(const float4*)&ks[kq + 8 * j][d4 * 4];
                    acc[j] += e.x * kv.x + e.y * kv.y + e.z * kv.z + e.w * kv.w;
                }
            }
            #pragma unroll
            for (int j = 0; j < 4; ++j)
                ek[(size_t)(bid * 32 + sl) * K + kq + 8 * j] = acc[j];
        }
    }
}

// ---------------------------------------------------------------------------
// Recurrence. Block = (b, 16-row half of K); 512 threads = 8 waves; wave w
// owns cols [32w,32w+32) = 2 sub-tiles. Lane (n=lane&15, quad=lane>>4):
// C/D row = quad*4+reg, col = 32w+16sub+n.
// U f16 hi/lo frags = 128 AGPRs/wave (asm "+a" pin, R8-proven).
// R10-R12 barrier A/B: __syncthreads()=109µs; raw lgkmcnt-only barrier
// (+/-setprio) = 119-123µs. The vmcnt(0) drain is FREE (prefetches complete
// while waves wait at the barrier anyway); the asm "memory" clobbers cost
// ~10µs of compiler scheduling. KEEP __syncthreads().
// setprio: negative here (lockstep barrier-synced structure, m190).
// ek is indexed by ABSOLUTE entity -> kh offset required (R3 bug).
// ---------------------------------------------------------------------------
__global__ __launch_bounds__(512, 2) void recur_kernel(
    const float* __restrict__ enc, const float* __restrict__ eWp,
    const float* __restrict__ keysV, const float* __restrict__ ek,
    const float* __restrict__ U, const int* __restrict__ mask,
    float* __restrict__ out) {
    const int b  = blockIdx.x >> 1;
    const int kh = (blockIdx.x & 1) * KH;
    const int t = threadIdx.x;
    const int wave = t >> 6, lane = t & 63;
    const int n = lane & 15, quad = lane >> 4;

    __shared__ u16 hF[2][KH][HSTR];      // 2 x 8.1 KB, f16 h planes
    __shared__ float redN[2][KH][NW];
    __shared__ float redG[2][KH][NW];

    // ---- preload U B-fragments (f16 hi/lo): 2 subs x 8 kt -> 128 AGPRs ----
    f16x8 Uhi[NSUB][8], Ulo[NSUB][8];
    #pragma unroll
    for (int sub = 0; sub < NSUB; ++sub) {
        const int col = wave * 32 + sub * 16 + n;
        #pragma unroll
        for (int kt = 0; kt < 8; ++kt) {
            #pragma unroll
            for (int j = 0; j < 8; ++j) {
                const int k = kt * 32 + quad * 8 + j;
                const float u = U[(size_t)k * D + col];
                const _Float16 uh = (_Float16)u;
                Uhi[sub][kt][j] = uh;
                Ulo[sub][kt][j] = (_Float16)(u - (float)uh);
            }
        }
    }
    #pragma unroll
    for (int sub = 0; sub < NSUB; ++sub)
        #pragma unroll
        for (int kt = 0; kt < 8; ++kt)
            asm volatile("" : "+a"(Uhi[sub][kt]), "+a"(Ulo[sub][kt]));

    // ---- per-lane state ----
    float upv[4][NSUB];
    float rn[4];
    float keysVc[4][NSUB];
    #pragma unroll
    for (int reg = 0; reg < 4; ++reg) {
        rn[reg] = 1.f;
        const size_t base = (size_t)(b * K + kh + quad * 4 + reg) * D;
        #pragma unroll
        for (int sub = 0; sub < NSUB; ++sub) {
            upv[reg][sub] = 0.f;
            keysVc[reg][sub] = keysV[base + wave * 32 + sub * 16 + n];
        }
    }

    const int* bm = mask + b * S;
    unsigned long long rem = __ballot(bm[lane & 63] != 0);

    float eWc[NSUB];
    float4 ekv = make_float4(0.f, 0.f, 0.f, 0.f);
    #pragma unroll
    for (int sub = 0; sub < NSUB; ++sub) eWc[sub] = 0.f;
    if (rem) {
        const int s0 = (int)__builtin_ctzll(rem);
        const size_t eo = (size_t)(b * S + s0) * D;
        #pragma unroll
        for (int sub = 0; sub < NSUB; ++sub)
            eWc[sub] = eWp[eo + wave * 32 + sub * 16 + n];
        ekv = *(const float4*)(ek + (size_t)(b * S + s0) * K + kh + quad * 4);
    }

    int p = 0, q = 0;
    bool first = true;
    while (rem) {
        rem &= rem - 1;
        const int sn = rem ? (int)__builtin_ctzll(rem) : -1;

        // ---- issue next-step e load early (covered by MFMA) ----
        float e_n[NSUB];
        #pragma unroll
        for (int sub = 0; sub < NSUB; ++sub) e_n[sub] = 0.f;
        if (sn >= 0) {
            const size_t eo = (size_t)(b * S + sn) * D;
            #pragma unroll
            for (int sub = 0; sub < NSUB; ++sub)
                e_n[sub] = enc[eo + wave * 32 + sub * 16 + n];
        }

        // ---- MFMA: acc = h_prev @ (Uhi,Ulo), 4 indep chains of 8 ----
        f32x4 acc[NSUB][2];
        #pragma unroll
        for (int sub = 0; sub < NSUB; ++sub) {
            acc[sub][0] = (f32x4){0.f, 0.f, 0.f, 0.f};
            acc[sub][1] = (f32x4){0.f, 0.f, 0.f, 0.f};
        }
        if (!first) {
            #pragma unroll
            for (int kt = 0; kt < 8; ++kt) {
                const f16x8 av = *(const f16x8*)&hF[p][n][kt * 32 + quad * 8];
                #pragma unroll
                for (int sub = 0; sub < NSUB; ++sub) {
                    acc[sub][0] = __builtin_amdgcn_mfma_f32_16x16x32_f16(av, Uhi[sub][kt], acc[sub][0], 0, 0, 0);
                    acc[sub][1] = __builtin_amdgcn_mfma_f32_16x16x32_f16(av, Ulo[sub][kt], acc[sub][1], 0, 0, 0);
                }
            }
        }

        // ---- gate ----
        float gate[4];
        #pragma unroll
        for (int reg = 0; reg < 4; ++reg) {
            const float ekb = (reg == 0) ? ekv.x : (reg == 1) ? ekv.y
                            : (reg == 2) ? ekv.z : ekv.w;
            float g = ekb;
            if (!first) {
                const float* rg = redG[q ^ 1][quad * 4 + reg];
                const float4 g0 = *(const float4*)rg;
                const float4 g1 = *(const float4*)(rg + 4);
                g += rn[reg] * (g0.x + g0.y + g0.z + g0.w +
                                g1.x + g1.y + g1.z + g1.w);
            }
            gate[reg] = 1.f / (1.f + __expf(-g));
        }

        // ---- update + f16 h write + norm/gate-dot partials ----
        const int pw = p ^ 1;
        float pn[4], gd[4];
        #pragma unroll
        for (int reg = 0; reg < 4; ++reg) {
            const int row = quad * 4 + reg;
            float sq = 0.f, dv = 0.f;
            #pragma unroll
            for (int sub = 0; sub < NSUB; ++sub) {
                const float asum = acc[sub][0][reg] + acc[sub][1][reg];
                float ht = rn[reg] * asum + keysVc[reg][sub] + eWc[sub];
                ht = fmaxf(ht, 0.f);
                const float u2 = rn[reg] * upv[reg][sub] + gate[reg] * ht;
                upv[reg][sub] = u2;
                sq += u2 * u2;
                dv += u2 * e_n[sub];
                hF[pw][row][wave * 32 + sub * 16 + n] = h_bits((_Float16)u2);
            }
            pn[reg] = sq;
            gd[reg] = dv;
        }

        // ---- reload step-invariants IN PLACE (last use passed) ----
        if (sn >= 0) {
            const size_t eo = (size_t)(b * S + sn) * D;
            #pragma unroll
            for (int sub = 0; sub < NSUB; ++sub)
                eWc[sub] = eWp[eo + wave * 32 + sub * 16 + n];
            ekv = *(const float4*)(ek + (size_t)(b * S + sn) * K + kh + quad * 4);
        }

        #pragma unroll
        for (int m = 1; m <= 8; m <<= 1) {
            #pragma unroll
            for (int reg = 0; reg < 4; ++reg) {
                pn[reg] += __shfl_xor(pn[reg], m);
                gd[reg] += __shfl_xor(gd[reg], m);
            }
        }
        if (n == 0) {
            #pragma unroll
            for (int reg = 0; reg < 4; ++reg) {
                redN[q][quad * 4 + reg][wave] = pn[reg];
                redG[q][quad * 4 + reg][wave] = gd[reg];
            }
        }

        __syncthreads();   // the ONLY barrier (R12: proven faster than raw
                           // lgkmcnt-only s_barrier by ~10µs)

        #pragma unroll
        for (int reg = 0; reg < 4; ++reg) {
            const float* rp = redN[q][quad * 4 + reg];
            const float4 r0 = *(const float4*)rp;
            const float4 r1 = *(const float4*)(rp + 4);
            rn[reg] = rsqrtf(fmaxf(r0.x + r0.y + r0.z + r0.w +
                                   r1.x + r1.y + r1.z + r1.w, 1e-12f));
        }
        p ^= 1; q ^= 1; first = false;
    }

    #pragma unroll
    for (int reg = 0; reg < 4; ++reg) {
        const size_t base = (size_t)(b * K + kh + quad * 4 + reg) * D;
        #pragma unroll
        for (int sub = 0; sub < NSUB; ++sub)
            out[base + wave * 32 + sub * 16 + n] = rn[reg] * upv[reg][sub];
    }
}

extern "C" void kernel_launch(void* const* d_in, const int* in_sizes, int n_in,
                              void* d_out, int out_size, void* d_ws, size_t ws_size,
                              hipStream_t stream) {
    const int*   prgrph = (const int*)d_in[0];
    const void*  pmask  = d_in[1];
    const float* keys   = (const float*)d_in[2];
    const float* E      = (const float*)d_in[3];
    const float* U      = (const float*)d_in[4];
    const float* V      = (const float*)d_in[5];
    const float* W      = (const float*)d_in[6];
    float* out = (float*)d_out;

    float* ws_enc   = (float*)d_ws;                          // B*S*D  (8 MB)
    float* ws_eW    = ws_enc + (size_t)B * S * D;            // B*S*D  (8 MB)
    float* ws_keysV = ws_eW  + (size_t)B * S * D;            // B*K*D  (4 MB)
    float* ws_ek    = ws_keysV + (size_t)B * K * D;          // B*S*K  (1 MB)
    int*   ws_mask  = (int*)(ws_ek + (size_t)B * S * K);     // B*S

    mask_kernel<<<32, 256, 0, stream>>>(pmask, ws_mask);
    pre_kernel<<<(B * S) / 32 + (B * K) / 32, 256, 0, stream>>>(
        prgrph, E, W, V, keys, ws_mask, ws_enc, ws_eW, ws_keysV, ws_ek);
    recur_kernel<<<B * (K / KH), 512, 0, stream>>>(
        ws_enc, ws_eW, ws_keysV, ws_ek, U, ws_mask, out);
}